// Round 1
// baseline (172.901 us; speedup 1.0000x reference)
//
#include <hip/hip_runtime.h>
#include <math.h>

#define SEQ 2048
#define NH 8
#define HD 128
#define DIMF 1024
#define LOG2E 1.4426950408889634f
#define INVTAU 0.08838834764831845f

typedef __attribute__((ext_vector_type(8))) short bf16x8;
typedef __attribute__((ext_vector_type(8))) unsigned short us8;
typedef __attribute__((ext_vector_type(4))) float f32x4;
typedef __attribute__((ext_vector_type(16))) float f32x16;

// persistent scratch (fully rewritten every launch; no stale-state dependence)
__device__ float g_itacc[NH*SEQ];
__device__ float g_ftacc[NH*SEQ];
__device__ float g_aL[NH*SEQ];     // (itilde - csum) * log2e
__device__ float g_cmL[NH*SEQ];    // cummax(a) * log2e
__device__ float g_en[NH*SEQ];     // exp(-(csum + cummax)) = exp(-max_d)
__device__ unsigned short g_Qb[NH*SEQ*HD];  // bf16, [h][s][d]
__device__ unsigned short g_Kb[NH*SEQ*HD];
__device__ unsigned short g_Vb[NH*SEQ*HD];
__device__ unsigned short g_Vt[NH*HD*SEQ];  // bf16, [h][d][s]  (V transposed)
__device__ unsigned short g_Wb[16*3072];    // bf16, rows 0..7 = Wi, 8..15 = Wf
// j-chunk partials: 640 slots (8 heads x 80 chunk-slots)
__device__ float g_Opart[640*64*128];       // fp32 partial O tiles
__device__ float g_Spart[640*64];           // fp32 partial rowsums

__device__ __forceinline__ unsigned short f2bf(float x) {
  unsigned u = __float_as_uint(x);
  u += 0x7fffu + ((u >> 16) & 1u);   // RNE
  return (unsigned short)(u >> 16);
}

__device__ __forceinline__ unsigned packbf(float lo, float hi) {
  return (unsigned)f2bf(lo) | ((unsigned)f2bf(hi) << 16);
}

// ------- kernel 1: q/k/v fp32 -> bf16 [h][s][d]  +  Wi/Wf -> bf16 (merged) -------
__global__ __launch_bounds__(256) void convert_kernel(const float* __restrict__ q,
                                                      const float* __restrict__ k,
                                                      const float* __restrict__ v,
                                                      const float* __restrict__ Wi,
                                                      const float* __restrict__ Wf) {
  const int bid = blockIdx.x;
  if (bid < 6144) {
    const int s = bid & 2047;
    const int t = bid >> 11;
    const float* src = (t == 0) ? q : (t == 1) ? k : v;
    unsigned short* dst = (t == 0) ? g_Qb : (t == 1) ? g_Kb : g_Vb;
    const int c = threadIdx.x * 4;
    const float4 f = *(const float4*)(src + s*DIMF + c);
    const int h = c >> 7, d = c & 127;
    ushort4 u;
    u.x = f2bf(f.x); u.y = f2bf(f.y); u.z = f2bf(f.z); u.w = f2bf(f.w);
    *(ushort4*)(dst + (h*SEQ + s)*HD + d) = u;
  } else {
    const int gid = (bid - 6144) * 256 + threadIdx.x;
    const int e4 = gid * 4;           // 48 blocks * 1024 = 49152 = 16*3072 exactly
    const int p = e4 / 3072;
    const int c = e4 % 3072;
    const float* src = (p < 8) ? (Wi + p*3072 + c) : (Wf + (p-8)*3072 + c);
    const float4 f = *(const float4*)src;
    ushort4 u;
    u.x = f2bf(f.x); u.y = f2bf(f.y); u.z = f2bf(f.z); u.w = f2bf(f.w);
    *(ushort4*)(g_Wb + p*3072 + c) = u;
  }
}

// ------- kernel 2: V transpose  g_Vb[h][s][d] -> g_Vt[h][d][s] -------
__global__ __launch_bounds__(256) void vtrans_kernel() {
  __shared__ __align__(16) unsigned short Ts[64*72];
  const int h  = blockIdx.x;
  const int s0 = blockIdx.y * 64;
  const int d0 = blockIdx.z * 64;
  const int t = threadIdx.x;
  { // load 64 s-rows x 64 d-cols, coalesced
    const int sr = t >> 2;
    const int c  = (t & 3) * 16;
    const unsigned short* src = g_Vb + (h*SEQ + s0 + sr)*HD + d0 + c;
    *(us8*)&Ts[sr*72 + c]     = *(const us8*)&src[0];
    *(us8*)&Ts[sr*72 + c + 8] = *(const us8*)&src[8];
  }
  __syncthreads();
  { // store: wave w covers s-cols [w*16,w*16+16), lane l = output d-row
    const int w = t >> 6, l = t & 63;
    unsigned short outv[16];
    #pragma unroll
    for (int j = 0; j < 16; ++j) outv[j] = Ts[(w*16 + j)*72 + l];
    unsigned short* dst = g_Vt + (h*HD + d0 + l)*SEQ + s0 + w*16;
    *(us8*)&dst[0] = *(us8*)&outv[0];
    *(us8*)&dst[8] = *(us8*)&outv[8];
  }
}

// ------- kernel 3: gate projections via MFMA (M=2048, N=16, K=3072) -------
__global__ __launch_bounds__(256) void gates_kernel() {
  __shared__ f32x4 red[4][64];
  const int tid = threadIdx.x;
  const int wave = tid >> 6, lane = tid & 63;
  const int q4 = lane >> 4, l16 = lane & 15;
  const int s0 = blockIdx.x * 16;
  f32x4 acc = {0.f, 0.f, 0.f, 0.f};
  #pragma unroll 8
  for (int ks = wave*24; ks < wave*24 + 24; ++ks) {
    const int k0 = ks*32 + q4*8;          // global k of this lane's 8 elems
    const int tsel = k0 >> 10;
    const int rem = k0 & 1023;
    const int hh = rem >> 7, dd = rem & 127;
    const unsigned short* base = (tsel == 0) ? g_Qb : (tsel == 1) ? g_Kb : g_Vb;
    const bf16x8 a = *(const bf16x8*)&base[(hh*SEQ + s0 + l16)*HD + dd];
    const bf16x8 b = *(const bf16x8*)&g_Wb[l16*3072 + k0];
    acc = __builtin_amdgcn_mfma_f32_16x16x32_bf16(a, b, acc, 0, 0, 0);
  }
  red[wave][lane] = acc;
  __syncthreads();
  if (wave == 0) {
    f32x4 s = red[0][lane];
    #pragma unroll
    for (int w = 1; w < 4; ++w) s += red[w][lane];
    #pragma unroll
    for (int r = 0; r < 4; ++r) {
      const int sg = s0 + 4*q4 + r;       // C/D: row = quad*4+reg, col = l16
      if (l16 < 8) g_itacc[l16*SEQ + sg] = s[r];
      else         g_ftacc[(l16-8)*SEQ + sg] = s[r];
    }
  }
}

// ------- kernel 4: per-head scans (block scan, 256 threads, 8 elems/thread) -------
__global__ __launch_bounds__(256) void scan_kernel(const float* __restrict__ Wi_b,
                                                   const float* __restrict__ Wf_b) {
  __shared__ float Wsum[4];
  __shared__ float Wmax[4];
  const int h = blockIdx.x;
  const int t = threadIdx.x;
  const int wave = t >> 6, lane = t & 63;
  const float ib = Wi_b[h];
  const float fb = Wf_b[h];
  const int base = h*SEQ + t*8;

  float it[8], ft[8];
  *(float4*)&it[0] = *(const float4*)&g_itacc[base];
  *(float4*)&it[4] = *(const float4*)&g_itacc[base+4];
  *(float4*)&ft[0] = *(const float4*)&g_ftacc[base];
  *(float4*)&ft[4] = *(const float4*)&g_ftacc[base+4];

  float cs[8];
  float run = 0.f;
  #pragma unroll
  for (int j = 0; j < 8; ++j) {
    const float f = ft[j] + fb;
    const float ls = fminf(f, 0.f) - log1pf(expf(-fabsf(f)));  // logsigmoid
    run += ls;
    cs[j] = run;
  }
  float x = run;
  #pragma unroll
  for (int off = 1; off < 64; off <<= 1) {
    const float tv = __shfl_up(x, off, 64);
    if (lane >= off) x += tv;
  }
  const float wexcl = x - run;
  if (lane == 63) Wsum[wave] = x;
  __syncthreads();
  float boff = 0.f;
  #pragma unroll
  for (int w = 0; w < 4; ++w) if (w < wave) boff += Wsum[w];
  const float cbase = boff + wexcl;

  float a[8], am[8], csum[8];
  float m = -__builtin_inff();
  #pragma unroll
  for (int j = 0; j < 8; ++j) {
    csum[j] = cbase + cs[j];
    a[j] = (it[j] + ib) - csum[j];
    m = fmaxf(m, a[j]);
    am[j] = m;
  }
  float y = m;
  #pragma unroll
  for (int off = 1; off < 64; off <<= 1) {
    const float tv = __shfl_up(y, off, 64);
    if (lane >= off) y = fmaxf(y, tv);
  }
  float e = __shfl_up(y, 1, 64);
  if (lane == 0) e = -__builtin_inff();
  if (lane == 63) Wmax[wave] = y;
  __syncthreads();
  float bmax = -__builtin_inff();
  #pragma unroll
  for (int w = 0; w < 4; ++w) if (w < wave) bmax = fmaxf(bmax, Wmax[w]);
  const float pre = fmaxf(bmax, e);

  float oa[8], ocm[8], oen[8];
  #pragma unroll
  for (int j = 0; j < 8; ++j) {
    const float cm = fmaxf(pre, am[j]);
    oa[j]  = a[j] * LOG2E;
    ocm[j] = cm * LOG2E;
    oen[j] = expf(-(csum[j] + cm));
  }
  *(float4*)&g_aL[base]    = *(float4*)&oa[0];
  *(float4*)&g_aL[base+4]  = *(float4*)&oa[4];
  *(float4*)&g_cmL[base]   = *(float4*)&ocm[0];
  *(float4*)&g_cmL[base+4] = *(float4*)&ocm[4];
  *(float4*)&g_en[base]    = *(float4*)&oen[0];
  *(float4*)&g_en[base+4]  = *(float4*)&oen[4];
}

// ------- kernel 5: j-chunked decay attention, barrier-free swapped 32x32 MFMA -------
// grid = (80 chunk-slots, 8 heads). Slot x -> (iT, c): group g = iT>>3 has
// g+1 chunks of <=8 j-tiles. Per wave (wr=i-half, wc=j-half):
//   S^T = K·Q^T via mfma_32x32x16 (i = lane&31 -> cm lane-local),
//   P in registers, P->bf16 A-frags via pack+permlane32_swap (no LDS roundtrip),
//   PV accumulates 32i x 128d partial (its j-half). K/V^T read straight from
//   global (L2-resident); LDS only used once in the epilogue to sum wc halves.
__global__ __launch_bounds__(256, 2) void attn1_kernel() {
  __shared__ float Osum[2][32][128];   // 32 KB: wc=0 partial O per i-half
  __shared__ float Sred[64][2];

  const int y = blockIdx.x;
  const int h = blockIdx.y;
  // decode slot -> (iT, chunk)
  int g, s0g;
  if      (y < 8)  { g = 0; s0g = 0;  }
  else if (y < 24) { g = 1; s0g = 8;  }
  else if (y < 48) { g = 2; s0g = 24; }
  else             { g = 3; s0g = 48; }
  const int rel = y - s0g;
  const int iT  = 8*g + rel/(g+1);
  const int ch  = rel - (rel/(g+1))*(g+1);
  const int slot = h*80 + y;
  const int i0 = iT*64;
  const int jt0 = ch*8;
  const int jt1 = (jt0 + 8 < iT + 1) ? (jt0 + 8) : (iT + 1);

  const int tid  = threadIdx.x;
  const int wave = tid >> 6;
  const int lane = tid & 63;
  const int l31  = lane & 31;
  const int hi   = lane >> 5;
  const int wr   = wave >> 1;          // i-half (32 rows)
  const int wc   = wave & 1;           // j-half (32 cols)

  // Q B-fragments for this wave's 32 i-rows: B[k=d][n=i], n = lane&31
  bf16x8 qf[8];
  {
    const unsigned short* Qg = g_Qb + (h*SEQ + i0 + 32*wr + l31)*HD + hi*8;
    #pragma unroll
    for (int ks = 0; ks < 8; ++ks) qf[ks] = *(const bf16x8*)&Qg[ks*16];
  }
  const float cm = g_cmL[h*SEQ + i0 + 32*wr + l31];
  const int   ig = i0 + 32*wr + l31;

  f32x16 acc[4];
  #pragma unroll
  for (int td = 0; td < 4; ++td)
    #pragma unroll
    for (int e = 0; e < 16; ++e) acc[td][e] = 0.f;
  float rs_sum = 0.f;

  const unsigned short* Kg  = g_Kb + (h*SEQ + 32*wc + l31)*HD + hi*8;
  const unsigned short* Vg  = g_Vt + (h*HD + l31)*SEQ + 32*wc + hi*8;
  const float*          aLg = g_aL + h*SEQ + 32*wc + 4*hi;

  for (int jt = jt0; jt < jt1; ++jt) {
    const int j0 = jt*64;
    // K A-fragments: A[m=j][k=d], m = lane&31  (global, L2-hit)
    bf16x8 kf[8];
    #pragma unroll
    for (int ks = 0; ks < 8; ++ks) kf[ks] = *(const bf16x8*)&Kg[j0*HD + ks*16];
    // aL for this wave's 32 j: j_loc = 8*rq + 4*hi + (r&3)
    float4 aLq[4];
    #pragma unroll
    for (int rq = 0; rq < 4; ++rq) aLq[rq] = *(const float4*)&aLg[j0 + 8*rq];

    // S^T = K·Q^T  (two interleaved acc chains for MFMA ILP)
    f32x16 a0, a1;
    #pragma unroll
    for (int e = 0; e < 16; ++e) { a0[e] = 0.f; a1[e] = 0.f; }
    #pragma unroll
    for (int ks = 0; ks < 8; ks += 2) {
      a0 = __builtin_amdgcn_mfma_f32_32x32x16_bf16(kf[ks],   qf[ks],   a0, 0, 0, 0);
      a1 = __builtin_amdgcn_mfma_f32_32x32x16_bf16(kf[ks+1], qf[ks+1], a1, 0, 0, 0);
    }

    const bool diag = (jt == iT);
    const int jbase = j0 + 32*wc + 4*hi;

    // P + in-register transpose to PV A-frags, then PV — per 16-j half
    #pragma unroll
    for (int ph = 0; ph < 2; ++ph) {
      float pv[8];
      #pragma unroll
      for (int rr = 0; rr < 8; ++rr) {
        const int r  = 8*ph + rr;
        const int rq = r >> 2;
        const float aL = ((const float*)&aLq[rq])[r & 3];
        float p = (a0[r] + a1[r]) * (exp2f(aL - cm) * INVTAU);
        const int jg = jbase + 8*rq + (r & 3);
        if (diag && jg > ig) p = 0.f;
        rs_sum += p;
        pv[rr] = p;
      }
      const unsigned w0 = packbf(pv[0], pv[1]);
      const unsigned w1 = packbf(pv[2], pv[3]);
      const unsigned w2 = packbf(pv[4], pv[5]);
      const unsigned w3 = packbf(pv[6], pv[7]);
      const auto s0 = __builtin_amdgcn_permlane32_swap(w0, w2, false, false);
      const auto s1 = __builtin_amdgcn_permlane32_swap(w1, w3, false, false);
      union { unsigned u[4]; bf16x8 v; } fr;
      fr.u[0] = s0[0]; fr.u[1] = s1[0]; fr.u[2] = s0[1]; fr.u[3] = s1[1];
      // V B-fragments: B[k=j][n=d], n = lane&31 (row of V^T, contiguous 16B)
      #pragma unroll
      for (int td = 0; td < 4; ++td) {
        const bf16x8 vb = *(const bf16x8*)&Vg[(32*td)*SEQ + j0 + 16*ph];
        acc[td] = __builtin_amdgcn_mfma_f32_32x32x16_bf16(fr.v, vb, acc[td], 0, 0, 0);
      }
    }
  }

  // rowsum: lane holds its i's sum over its 16 j — combine hi halves, then wc via LDS
  rs_sum += __shfl_xor(rs_sum, 32, 64);
  if (hi == 0) Sred[32*wr + l31][wc] = rs_sum;

  // combine wc halves' partial O via LDS, write fp32 partial tile
  if (wc == 0) {
    #pragma unroll
    for (int td = 0; td < 4; ++td)
      #pragma unroll
      for (int r = 0; r < 16; ++r) {
        const int row = (r & 3) + 8*(r >> 2) + 4*hi;
        Osum[wr][row][32*td + l31] = acc[td][r];
      }
  }
  __syncthreads();
  if (wc == 1) {
    float* Ob = g_Opart + slot*(64*128);
    #pragma unroll
    for (int td = 0; td < 4; ++td)
      #pragma unroll
      for (int r = 0; r < 16; ++r) {
        const int row = (r & 3) + 8*(r >> 2) + 4*hi;
        Ob[(32*wr + row)*128 + 32*td + l31] = acc[td][r] + Osum[wr][row][32*td + l31];
      }
  }
  if (tid < 64) g_Spart[slot*64 + tid] = Sred[tid][0] + Sred[tid][1];
}

// ------- kernel 6: reduce partials + maxit normalize + GroupNorm -------
// grid = (8 heads, 32 i-tiles), 256 threads: thread -> (row = t>>2, quarter = t&3)
__global__ __launch_bounds__(256) void reduce_kernel(const float* __restrict__ gnw,
                                                     const float* __restrict__ gnb,
                                                     float* __restrict__ out) {
  const int h  = blockIdx.x;
  const int iT = blockIdx.y;
  const int t  = threadIdx.x;
  const int r  = t >> 2;
  const int qd = t & 3;
  const int qq = iT >> 3;
  const int nch = qq + 1;
  const int slot0 = h*80 + iT + 4*qq*(qq-1) + qq*(iT & 7);

  float acc[32];
  #pragma unroll
  for (int e = 0; e < 32; ++e) acc[e] = 0.f;
  float S = 0.f;
  for (int c = 0; c < nch; ++c) {
    const float* Ob = g_Opart + (slot0 + c)*(64*128) + r*128 + qd*32;
    #pragma unroll
    for (int kk = 0; kk < 8; ++kk) {
      const float4 f = *(const float4*)&Ob[kk*4];
      acc[kk*4+0] += f.x; acc[kk*4+1] += f.y; acc[kk*4+2] += f.z; acc[kk*4+3] += f.w;
    }
    S += g_Spart[(slot0 + c)*64 + r];
  }

  const float en = g_en[h*SEQ + iT*64 + r];
  const float sc = 1.f / (fmaxf(fabsf(S), en) + 1e-6f);
  float s1 = 0.f, s2 = 0.f;
  #pragma unroll
  for (int e = 0; e < 32; ++e) {
    const float xv = acc[e] * sc;
    acc[e] = xv;
    s1 += xv;
    s2 += xv * xv;
  }
  s1 += __shfl_xor(s1, 1, 4); s2 += __shfl_xor(s2, 1, 4);
  s1 += __shfl_xor(s1, 2, 4); s2 += __shfl_xor(s2, 2, 4);
  const float mean = s1 * (1.f/128.f);
  const float var  = s2 * (1.f/128.f) - mean*mean;
  const float rstd = rsqrtf(var + 1e-5f);

  const float* gw = gnw + h*HD + qd*32;
  const float* gb = gnb + h*HD + qd*32;
  float* op = out + (iT*64 + r)*DIMF + h*HD + qd*32;
  #pragma unroll
  for (int kk = 0; kk < 8; ++kk) {
    const float4 w4 = *(const float4*)&gw[kk*4];
    const float4 b4 = *(const float4*)&gb[kk*4];
    float4 o;
    o.x = (acc[kk*4+0] - mean) * rstd * w4.x + b4.x;
    o.y = (acc[kk*4+1] - mean) * rstd * w4.y + b4.y;
    o.z = (acc[kk*4+2] - mean) * rstd * w4.z + b4.z;
    o.w = (acc[kk*4+3] - mean) * rstd * w4.w + b4.w;
    *(float4*)&op[kk*4] = o;
  }
}

extern "C" void kernel_launch(void* const* d_in, const int* in_sizes, int n_in,
                              void* d_out, int out_size, void* d_ws, size_t ws_size,
                              hipStream_t stream) {
  (void)in_sizes; (void)n_in; (void)out_size; (void)d_ws; (void)ws_size;
  const float* q    = (const float*)d_in[0];
  const float* k    = (const float*)d_in[1];
  const float* v    = (const float*)d_in[2];
  const float* Wi_w = (const float*)d_in[3];
  const float* Wi_b = (const float*)d_in[4];
  const float* Wf_w = (const float*)d_in[5];
  const float* Wf_b = (const float*)d_in[6];
  const float* gnw  = (const float*)d_in[7];
  const float* gnb  = (const float*)d_in[8];
  float* out = (float*)d_out;

  convert_kernel<<<dim3(6192), 256, 0, stream>>>(q, k, v, Wi_w, Wf_w);
  vtrans_kernel<<<dim3(NH, SEQ/64, HD/64), 256, 0, stream>>>();
  gates_kernel<<<dim3(128), 256, 0, stream>>>();
  scan_kernel<<<dim3(NH), 256, 0, stream>>>(Wi_b, Wf_b);
  attn1_kernel<<<dim3(80, NH), 256, 0, stream>>>();
  reduce_kernel<<<dim3(NH, SEQ/64), 256, 0, stream>>>(gnw, gnb, out);
}

// Round 2
// 168.494 us; speedup vs baseline: 1.0262x; 1.0262x over previous
//
#include <hip/hip_runtime.h>
#include <math.h>

#define SEQ 2048
#define NH 8
#define HD 128
#define DIMF 1024
#define LOG2E 1.4426950408889634f
#define INVTAU 0.08838834764831845f
#define NSLOT 144   // per-head chunk-slots, chunk = 4 j-tiles

typedef __attribute__((ext_vector_type(8))) short bf16x8;
typedef __attribute__((ext_vector_type(8))) unsigned short us8;
typedef __attribute__((ext_vector_type(4))) float f32x4;
typedef __attribute__((ext_vector_type(16))) float f32x16;

// persistent scratch (fully rewritten every launch; no stale-state dependence)
__device__ float g_itacc[NH*SEQ];
__device__ float g_ftacc[NH*SEQ];
__device__ float g_aL[NH*SEQ];     // (itilde - csum) * log2e
__device__ float g_cmL[NH*SEQ];    // cummax(a) * log2e
__device__ float g_en[NH*SEQ];     // exp(-(csum + cummax)) = exp(-max_d)
__device__ unsigned short g_Qb[NH*SEQ*HD];  // bf16, [h][s][d]
__device__ unsigned short g_Kb[NH*SEQ*HD];
__device__ unsigned short g_Vb[NH*SEQ*HD];
__device__ unsigned short g_Vt[NH*HD*SEQ];  // bf16, [h][d][s]  (V transposed)
__device__ unsigned short g_Wb[16*3072];    // bf16, rows 0..7 = Wi, 8..15 = Wf
// j-chunk partials: 1152 slots (8 heads x 144 chunk-slots)
__device__ float g_Opart[NH*NSLOT*64*128];  // fp32 partial O tiles
__device__ float g_Spart[NH*NSLOT*64];      // fp32 partial rowsums

__device__ __forceinline__ unsigned short f2bf(float x) {
  unsigned u = __float_as_uint(x);
  u += 0x7fffu + ((u >> 16) & 1u);   // RNE
  return (unsigned short)(u >> 16);
}

__device__ __forceinline__ unsigned packbf(float lo, float hi) {
  return (unsigned)f2bf(lo) | ((unsigned)f2bf(hi) << 16);
}

__device__ __forceinline__ void gload16(const unsigned short* g, unsigned short* l) {
  __builtin_amdgcn_global_load_lds(
      (const __attribute__((address_space(1))) unsigned int*)g,
      (__attribute__((address_space(3))) unsigned int*)l, 16, 0, 0);
}

// ------- kernel 1: q/k/v fp32 -> bf16 [h][s][d]  +  Wi/Wf -> bf16 (merged) -------
__global__ __launch_bounds__(256) void convert_kernel(const float* __restrict__ q,
                                                      const float* __restrict__ k,
                                                      const float* __restrict__ v,
                                                      const float* __restrict__ Wi,
                                                      const float* __restrict__ Wf) {
  const int bid = blockIdx.x;
  if (bid < 6144) {
    const int s = bid & 2047;
    const int t = bid >> 11;
    const float* src = (t == 0) ? q : (t == 1) ? k : v;
    unsigned short* dst = (t == 0) ? g_Qb : (t == 1) ? g_Kb : g_Vb;
    const int c = threadIdx.x * 4;
    const float4 f = *(const float4*)(src + s*DIMF + c);
    const int h = c >> 7, d = c & 127;
    ushort4 u;
    u.x = f2bf(f.x); u.y = f2bf(f.y); u.z = f2bf(f.z); u.w = f2bf(f.w);
    *(ushort4*)(dst + (h*SEQ + s)*HD + d) = u;
  } else {
    const int gid = (bid - 6144) * 256 + threadIdx.x;
    const int e4 = gid * 4;           // 48 blocks * 1024 = 49152 = 16*3072 exactly
    const int p = e4 / 3072;
    const int c = e4 % 3072;
    const float* src = (p < 8) ? (Wi + p*3072 + c) : (Wf + (p-8)*3072 + c);
    const float4 f = *(const float4*)src;
    ushort4 u;
    u.x = f2bf(f.x); u.y = f2bf(f.y); u.z = f2bf(f.z); u.w = f2bf(f.w);
    *(ushort4*)(g_Wb + p*3072 + c) = u;
  }
}

// ------- kernel 2: V transpose  g_Vb[h][s][d] -> g_Vt[h][d][s] -------
__global__ __launch_bounds__(256) void vtrans_kernel() {
  __shared__ __align__(16) unsigned short Ts[64*72];
  const int h  = blockIdx.x;
  const int s0 = blockIdx.y * 64;
  const int d0 = blockIdx.z * 64;
  const int t = threadIdx.x;
  { // load 64 s-rows x 64 d-cols, coalesced
    const int sr = t >> 2;
    const int c  = (t & 3) * 16;
    const unsigned short* src = g_Vb + (h*SEQ + s0 + sr)*HD + d0 + c;
    *(us8*)&Ts[sr*72 + c]     = *(const us8*)&src[0];
    *(us8*)&Ts[sr*72 + c + 8] = *(const us8*)&src[8];
  }
  __syncthreads();
  { // store: wave w covers s-cols [w*16,w*16+16), lane l = output d-row
    const int w = t >> 6, l = t & 63;
    unsigned short outv[16];
    #pragma unroll
    for (int j = 0; j < 16; ++j) outv[j] = Ts[(w*16 + j)*72 + l];
    unsigned short* dst = g_Vt + (h*HD + d0 + l)*SEQ + s0 + w*16;
    *(us8*)&dst[0] = *(us8*)&outv[0];
    *(us8*)&dst[8] = *(us8*)&outv[8];
  }
}

// ------- kernel 3: gate projections via MFMA (M=2048, N=16, K=3072) -------
__global__ __launch_bounds__(256) void gates_kernel() {
  __shared__ f32x4 red[4][64];
  const int tid = threadIdx.x;
  const int wave = tid >> 6, lane = tid & 63;
  const int q4 = lane >> 4, l16 = lane & 15;
  const int s0 = blockIdx.x * 16;
  f32x4 acc = {0.f, 0.f, 0.f, 0.f};
  #pragma unroll 8
  for (int ks = wave*24; ks < wave*24 + 24; ++ks) {
    const int k0 = ks*32 + q4*8;          // global k of this lane's 8 elems
    const int tsel = k0 >> 10;
    const int rem = k0 & 1023;
    const int hh = rem >> 7, dd = rem & 127;
    const unsigned short* base = (tsel == 0) ? g_Qb : (tsel == 1) ? g_Kb : g_Vb;
    const bf16x8 a = *(const bf16x8*)&base[(hh*SEQ + s0 + l16)*HD + dd];
    const bf16x8 b = *(const bf16x8*)&g_Wb[l16*3072 + k0];
    acc = __builtin_amdgcn_mfma_f32_16x16x32_bf16(a, b, acc, 0, 0, 0);
  }
  red[wave][lane] = acc;
  __syncthreads();
  if (wave == 0) {
    f32x4 s = red[0][lane];
    #pragma unroll
    for (int w = 1; w < 4; ++w) s += red[w][lane];
    #pragma unroll
    for (int r = 0; r < 4; ++r) {
      const int sg = s0 + 4*q4 + r;       // C/D: row = quad*4+reg, col = l16
      if (l16 < 8) g_itacc[l16*SEQ + sg] = s[r];
      else         g_ftacc[(l16-8)*SEQ + sg] = s[r];
    }
  }
}

// ------- kernel 4: per-head scans (block scan, 256 threads, 8 elems/thread) -------
__global__ __launch_bounds__(256) void scan_kernel(const float* __restrict__ Wi_b,
                                                   const float* __restrict__ Wf_b) {
  __shared__ float Wsum[4];
  __shared__ float Wmax[4];
  const int h = blockIdx.x;
  const int t = threadIdx.x;
  const int wave = t >> 6, lane = t & 63;
  const float ib = Wi_b[h];
  const float fb = Wf_b[h];
  const int base = h*SEQ + t*8;

  float it[8], ft[8];
  *(float4*)&it[0] = *(const float4*)&g_itacc[base];
  *(float4*)&it[4] = *(const float4*)&g_itacc[base+4];
  *(float4*)&ft[0] = *(const float4*)&g_ftacc[base];
  *(float4*)&ft[4] = *(const float4*)&g_ftacc[base+4];

  float cs[8];
  float run = 0.f;
  #pragma unroll
  for (int j = 0; j < 8; ++j) {
    const float f = ft[j] + fb;
    const float ls = fminf(f, 0.f) - log1pf(expf(-fabsf(f)));  // logsigmoid
    run += ls;
    cs[j] = run;
  }
  float x = run;
  #pragma unroll
  for (int off = 1; off < 64; off <<= 1) {
    const float tv = __shfl_up(x, off, 64);
    if (lane >= off) x += tv;
  }
  const float wexcl = x - run;
  if (lane == 63) Wsum[wave] = x;
  __syncthreads();
  float boff = 0.f;
  #pragma unroll
  for (int w = 0; w < 4; ++w) if (w < wave) boff += Wsum[w];
  const float cbase = boff + wexcl;

  float a[8], am[8], csum[8];
  float m = -__builtin_inff();
  #pragma unroll
  for (int j = 0; j < 8; ++j) {
    csum[j] = cbase + cs[j];
    a[j] = (it[j] + ib) - csum[j];
    m = fmaxf(m, a[j]);
    am[j] = m;
  }
  float y = m;
  #pragma unroll
  for (int off = 1; off < 64; off <<= 1) {
    const float tv = __shfl_up(y, off, 64);
    if (lane >= off) y = fmaxf(y, tv);
  }
  float e = __shfl_up(y, 1, 64);
  if (lane == 0) e = -__builtin_inff();
  if (lane == 63) Wmax[wave] = y;
  __syncthreads();
  float bmax = -__builtin_inff();
  #pragma unroll
  for (int w = 0; w < 4; ++w) if (w < wave) bmax = fmaxf(bmax, Wmax[w]);
  const float pre = fmaxf(bmax, e);

  float oa[8], ocm[8], oen[8];
  #pragma unroll
  for (int j = 0; j < 8; ++j) {
    const float cm = fmaxf(pre, am[j]);
    oa[j]  = a[j] * LOG2E;
    ocm[j] = cm * LOG2E;
    oen[j] = expf(-(csum[j] + cm));
  }
  *(float4*)&g_aL[base]    = *(float4*)&oa[0];
  *(float4*)&g_aL[base+4]  = *(float4*)&oa[4];
  *(float4*)&g_cmL[base]   = *(float4*)&ocm[0];
  *(float4*)&g_cmL[base+4] = *(float4*)&ocm[4];
  *(float4*)&g_en[base]    = *(float4*)&oen[0];
  *(float4*)&g_en[base+4]  = *(float4*)&oen[4];
}

// ------- kernel 5: j-chunked decay attention -------
// grid = (NH, 144): x = head -> linear%8 pins each head to one XCD (K/V L2-resident).
// Slot y -> (iT, ch), chunk = 4 j-tiles, group q = iT>>2 has q+1 chunks.
// Compute: swapped 32x32 MFMA (S^T = K.Q^T, i = lane&31), in-register P->bf16
// transpose via pack+permlane32_swap. Memory: K and V^T tiles staged to LDS via
// global_load_lds with XOR-swizzled SOURCE addresses (linear LDS dest), swizzled
// ds_read_b128 on the consume side. 2 barriers/tile. Epilogue Osum overlays Ks/Vt.
__global__ __launch_bounds__(256, 3) void attn1_kernel() {
  __shared__ __align__(16) unsigned char smem[33280];
  unsigned short* Ks = (unsigned short*)smem;            // 16 KB: [64 j][128 d] swz
  unsigned short* Vt = (unsigned short*)(smem + 16384);  // 16 KB: [128 d][64 j] swz
  float (*Osum)[32][128] = (float (*)[32][128])smem;     // 32 KB overlay (epilogue)
  float (*Sred)[2] = (float (*)[2])(smem + 32768);       // 512 B (no overlap)

  const int h = blockIdx.x;
  const int y = blockIdx.y;
  // decode slot -> (iT, chunk): group q occupies [2q(q+1), 2(q+1)(q+2))
  int q = 0, s0g = 0;
  while (y >= s0g + 4*(q+1)) { s0g += 4*(q+1); ++q; }
  const int rel = y - s0g;
  const int iT  = 4*q + rel/(q+1);
  const int ch  = rel - (rel/(q+1))*(q+1);
  const int slot = h*NSLOT + y;
  const int i0 = iT*64;
  const int jt0 = ch*4;
  const int jt1 = (jt0 + 4 < iT + 1) ? (jt0 + 4) : (iT + 1);

  const int tid  = threadIdx.x;
  const int wave = tid >> 6;
  const int lane = tid & 63;
  const int l31  = lane & 31;
  const int hi   = lane >> 5;
  const int wr   = wave >> 1;          // i-half (32 rows)
  const int wc   = wave & 1;           // j-half (32 cols)
  const int wbase = __builtin_amdgcn_readfirstlane(wave);

  // Q B-fragments for this wave's 32 i-rows: B[k=d][n=i], n = lane&31
  bf16x8 qf[8];
  {
    const unsigned short* Qg = g_Qb + (h*SEQ + i0 + 32*wr + l31)*HD + hi*8;
    #pragma unroll
    for (int ks = 0; ks < 8; ++ks) qf[ks] = *(const bf16x8*)&Qg[ks*16];
  }
  const float cm = g_cmL[h*SEQ + i0 + 32*wr + l31];
  const int   ig = i0 + 32*wr + l31;

  f32x16 acc[4];
  #pragma unroll
  for (int td = 0; td < 4; ++td)
    #pragma unroll
    for (int e = 0; e < 16; ++e) acc[td][e] = 0.f;
  float rs_sum = 0.f;

  const unsigned short* Kgh = g_Kb + h*SEQ*HD;
  const unsigned short* Vgh = g_Vt + h*HD*SEQ;
  const float*          aLg = g_aL + h*SEQ + 32*wc + 4*hi;

  // staging source offsets (lane-invariant across tiles):
  // K: LDS 16B-slot s=(wave*4+gi)*64+lane -> row r=s>>4, lds col c'=s&15,
  //    source col c = c' ^ (r&15)  (4-bit swizzle -> conflict-free reads)
  // V: slot s -> row d=s>>3, lds col c'=s&7, source col c = c' ^ (d&7)
  int pK[4], pV[4];
  #pragma unroll
  for (int gi = 0; gi < 4; ++gi) {
    const int s  = (wave*4 + gi)*64 + lane;
    const int rK = s >> 4;
    const int cK = (s & 15) ^ (rK & 15);
    pK[gi] = rK*HD + cK*8;
    const int dV = s >> 3;
    const int cV = (s & 7) ^ (dV & 7);
    pV[gi] = dV*SEQ + cV*8;
  }

  const int rI = 32*wc + l31;           // this wave's K-row for the A-frag
  const unsigned short* KsRow = &Ks[rI*128];
  const int swK = rI & 15;

  for (int jt = jt0; jt < jt1; ++jt) {
    const int j0 = jt*64;
    __syncthreads();                    // previous tile's LDS reads complete
    #pragma unroll
    for (int gi = 0; gi < 4; ++gi) {
      gload16(Kgh + j0*HD + pK[gi], &Ks[(wbase*4 + gi)*512]);
      gload16(Vgh + j0     + pV[gi], &Vt[(wbase*4 + gi)*512]);
    }
    float4 aLq[4];
    #pragma unroll
    for (int rq = 0; rq < 4; ++rq) aLq[rq] = *(const float4*)&aLg[j0 + 8*rq];
    asm volatile("s_waitcnt vmcnt(0)" ::: "memory");
    __syncthreads();                    // staged tile visible to all waves

    // S^T = K·Q^T  (two interleaved acc chains for MFMA ILP)
    f32x16 a0, a1;
    #pragma unroll
    for (int e = 0; e < 16; ++e) { a0[e] = 0.f; a1[e] = 0.f; }
    #pragma unroll
    for (int ks = 0; ks < 8; ks += 2) {
      const bf16x8 k0v = *(const bf16x8*)&KsRow[((ks*2 + hi)     ^ swK)*8];
      const bf16x8 k1v = *(const bf16x8*)&KsRow[(((ks+1)*2 + hi) ^ swK)*8];
      a0 = __builtin_amdgcn_mfma_f32_32x32x16_bf16(k0v, qf[ks],   a0, 0, 0, 0);
      a1 = __builtin_amdgcn_mfma_f32_32x32x16_bf16(k1v, qf[ks+1], a1, 0, 0, 0);
    }

    const bool diag = (jt == iT);
    const int jbase = j0 + 32*wc + 4*hi;

    // P + in-register transpose to PV A-frags, then PV — per 16-j half
    #pragma unroll
    for (int ph = 0; ph < 2; ++ph) {
      float pv[8];
      #pragma unroll
      for (int rr = 0; rr < 8; ++rr) {
        const int r  = 8*ph + rr;
        const int rq = r >> 2;
        const float aL = ((const float*)&aLq[rq])[r & 3];
        float p = (a0[r] + a1[r]) * (exp2f(aL - cm) * INVTAU);
        const int jg = jbase + 8*rq + (r & 3);
        if (diag && jg > ig) p = 0.f;
        rs_sum += p;
        pv[rr] = p;
      }
      const unsigned w0 = packbf(pv[0], pv[1]);
      const unsigned w1 = packbf(pv[2], pv[3]);
      const unsigned w2 = packbf(pv[4], pv[5]);
      const unsigned w3 = packbf(pv[6], pv[7]);
      const auto s0 = __builtin_amdgcn_permlane32_swap(w0, w2, false, false);
      const auto s1 = __builtin_amdgcn_permlane32_swap(w1, w3, false, false);
      union { unsigned u[4]; bf16x8 v; } fr;
      fr.u[0] = s0[0]; fr.u[1] = s1[0]; fr.u[2] = s0[1]; fr.u[3] = s1[1];
      // V B-frags: B[k=j][n=d] from swizzled Vt rows (d = 32*td + l31)
      #pragma unroll
      for (int td = 0; td < 4; ++td) {
        const int d = 32*td + l31;
        const bf16x8 vb = *(const bf16x8*)&Vt[d*64 + (((4*wc + 2*ph + hi) ^ (d & 7))*8)];
        acc[td] = __builtin_amdgcn_mfma_f32_32x32x16_bf16(fr.v, vb, acc[td], 0, 0, 0);
      }
    }
  }

  // rowsum: lane holds its i's sum over its 16 j — combine hi halves, then wc via LDS
  rs_sum += __shfl_xor(rs_sum, 32, 64);
  if (hi == 0) Sred[32*wr + l31][wc] = rs_sum;
  __syncthreads();                      // all LDS tile reads done; Sred written

  // combine wc halves' partial O via LDS overlay, write fp32 partial tile
  if (wc == 0) {
    #pragma unroll
    for (int td = 0; td < 4; ++td)
      #pragma unroll
      for (int r = 0; r < 16; ++r) {
        const int row = (r & 3) + 8*(r >> 2) + 4*hi;
        Osum[wr][row][32*td + l31] = acc[td][r];
      }
  }
  __syncthreads();
  if (wc == 1) {
    float* Ob = g_Opart + slot*(64*128);
    #pragma unroll
    for (int td = 0; td < 4; ++td)
      #pragma unroll
      for (int r = 0; r < 16; ++r) {
        const int row = (r & 3) + 8*(r >> 2) + 4*hi;
        Ob[(32*wr + row)*128 + 32*td + l31] = acc[td][r] + Osum[wr][row][32*td + l31];
      }
  }
  if (tid < 64) g_Spart[slot*64 + tid] = Sred[tid][0] + Sred[tid][1];
}

// ------- kernel 6: reduce partials + maxit normalize + GroupNorm -------
// grid = (8 heads, 32 i-tiles), 256 threads: thread -> (row = t>>2, quarter = t&3)
__global__ __launch_bounds__(256) void reduce_kernel(const float* __restrict__ gnw,
                                                     const float* __restrict__ gnb,
                                                     float* __restrict__ out) {
  const int h  = blockIdx.x;
  const int iT = blockIdx.y;
  const int t  = threadIdx.x;
  const int r  = t >> 2;
  const int qd = t & 3;
  const int qq = iT >> 2;
  const int nch = qq + 1;
  const int slot0 = h*NSLOT + 2*qq*(qq+1) + (iT & 3)*(qq + 1);

  float acc[32];
  #pragma unroll
  for (int e = 0; e < 32; ++e) acc[e] = 0.f;
  float S = 0.f;
  for (int c = 0; c < nch; ++c) {
    const float* Ob = g_Opart + (slot0 + c)*(64*128) + r*128 + qd*32;
    #pragma unroll
    for (int kk = 0; kk < 8; ++kk) {
      const float4 f = *(const float4*)&Ob[kk*4];
      acc[kk*4+0] += f.x; acc[kk*4+1] += f.y; acc[kk*4+2] += f.z; acc[kk*4+3] += f.w;
    }
    S += g_Spart[(slot0 + c)*64 + r];
  }

  const float en = g_en[h*SEQ + iT*64 + r];
  const float sc = 1.f / (fmaxf(fabsf(S), en) + 1e-6f);
  float s1 = 0.f, s2 = 0.f;
  #pragma unroll
  for (int e = 0; e < 32; ++e) {
    const float xv = acc[e] * sc;
    acc[e] = xv;
    s1 += xv;
    s2 += xv * xv;
  }
  s1 += __shfl_xor(s1, 1, 4); s2 += __shfl_xor(s2, 1, 4);
  s1 += __shfl_xor(s1, 2, 4); s2 += __shfl_xor(s2, 2, 4);
  const float mean = s1 * (1.f/128.f);
  const float var  = s2 * (1.f/128.f) - mean*mean;
  const float rstd = rsqrtf(var + 1e-5f);

  const float* gw = gnw + h*HD + qd*32;
  const float* gb = gnb + h*HD + qd*32;
  float* op = out + (iT*64 + r)*DIMF + h*HD + qd*32;
  #pragma unroll
  for (int kk = 0; kk < 8; ++kk) {
    const float4 w4 = *(const float4*)&gw[kk*4];
    const float4 b4 = *(const float4*)&gb[kk*4];
    float4 o;
    o.x = (acc[kk*4+0] - mean) * rstd * w4.x + b4.x;
    o.y = (acc[kk*4+1] - mean) * rstd * w4.y + b4.y;
    o.z = (acc[kk*4+2] - mean) * rstd * w4.z + b4.z;
    o.w = (acc[kk*4+3] - mean) * rstd * w4.w + b4.w;
    *(float4*)&op[kk*4] = o;
  }
}

extern "C" void kernel_launch(void* const* d_in, const int* in_sizes, int n_in,
                              void* d_out, int out_size, void* d_ws, size_t ws_size,
                              hipStream_t stream) {
  (void)in_sizes; (void)n_in; (void)out_size; (void)d_ws; (void)ws_size;
  const float* q    = (const float*)d_in[0];
  const float* k    = (const float*)d_in[1];
  const float* v    = (const float*)d_in[2];
  const float* Wi_w = (const float*)d_in[3];
  const float* Wi_b = (const float*)d_in[4];
  const float* Wf_w = (const float*)d_in[5];
  const float* Wf_b = (const float*)d_in[6];
  const float* gnw  = (const float*)d_in[7];
  const float* gnb  = (const float*)d_in[8];
  float* out = (float*)d_out;

  convert_kernel<<<dim3(6192), 256, 0, stream>>>(q, k, v, Wi_w, Wf_w);
  vtrans_kernel<<<dim3(NH, SEQ/64, HD/64), 256, 0, stream>>>();
  gates_kernel<<<dim3(128), 256, 0, stream>>>();
  scan_kernel<<<dim3(NH), 256, 0, stream>>>(Wi_b, Wf_b);
  attn1_kernel<<<dim3(NH, NSLOT), 256, 0, stream>>>();
  reduce_kernel<<<dim3(NH, SEQ/64), 256, 0, stream>>>(gnw, gnb, out);
}

// Round 3
// 145.831 us; speedup vs baseline: 1.1856x; 1.1554x over previous
//
#include <hip/hip_runtime.h>
#include <math.h>

#define SEQ 2048
#define NH 8
#define HD 128
#define DIMF 1024
#define LOG2E 1.4426950408889634f
#define INVTAU 0.08838834764831845f

typedef __attribute__((ext_vector_type(8))) short bf16x8;
typedef __attribute__((ext_vector_type(8))) unsigned short us8;
typedef __attribute__((ext_vector_type(4))) float f32x4;
typedef __attribute__((ext_vector_type(16))) float f32x16;

// persistent scratch (fully rewritten every launch; no stale-state dependence)
__device__ float g_itacc[NH*SEQ];
__device__ float g_ftacc[NH*SEQ];
__device__ float g_aL[NH*SEQ];     // (itilde - csum) * log2e
__device__ float g_cmL[NH*SEQ];    // cummax(a) * log2e
__device__ float g_en[NH*SEQ];     // exp(-(csum + cummax)) = exp(-max_d)
__device__ unsigned short g_Qb[NH*SEQ*HD];  // bf16, [h][s][d]
__device__ unsigned short g_Kb[NH*SEQ*HD];
__device__ unsigned short g_Vb[NH*SEQ*HD];
__device__ unsigned short g_Vt[NH*HD*SEQ];  // bf16, [h][d][s]  (V transposed)
__device__ unsigned short g_Wb[16*3072];    // bf16, rows 0..7 = Wi, 8..15 = Wf

__device__ __forceinline__ unsigned short f2bf(float x) {
  unsigned u = __float_as_uint(x);
  u += 0x7fffu + ((u >> 16) & 1u);   // RNE
  return (unsigned short)(u >> 16);
}

__device__ __forceinline__ unsigned packbf(float lo, float hi) {
  return (unsigned)f2bf(lo) | ((unsigned)f2bf(hi) << 16);
}

// ------- kernel 1: q/k/v fp32 -> bf16 [h][s][d]  +  Wi/Wf -> bf16 (merged) -------
__global__ __launch_bounds__(256) void convert_kernel(const float* __restrict__ q,
                                                      const float* __restrict__ k,
                                                      const float* __restrict__ v,
                                                      const float* __restrict__ Wi,
                                                      const float* __restrict__ Wf) {
  const int bid = blockIdx.x;
  if (bid < 6144) {
    const int s = bid & 2047;
    const int t = bid >> 11;
    const float* src = (t == 0) ? q : (t == 1) ? k : v;
    unsigned short* dst = (t == 0) ? g_Qb : (t == 1) ? g_Kb : g_Vb;
    const int c = threadIdx.x * 4;
    const float4 f = *(const float4*)(src + s*DIMF + c);
    const int h = c >> 7, d = c & 127;
    ushort4 u;
    u.x = f2bf(f.x); u.y = f2bf(f.y); u.z = f2bf(f.z); u.w = f2bf(f.w);
    *(ushort4*)(dst + (h*SEQ + s)*HD + d) = u;
  } else {
    const int gid = (bid - 6144) * 256 + threadIdx.x;
    const int e4 = gid * 4;           // 48 blocks * 1024 = 49152 = 16*3072 exactly
    const int p = e4 / 3072;
    const int c = e4 % 3072;
    const float* src = (p < 8) ? (Wi + p*3072 + c) : (Wf + (p-8)*3072 + c);
    const float4 f = *(const float4*)src;
    ushort4 u;
    u.x = f2bf(f.x); u.y = f2bf(f.y); u.z = f2bf(f.z); u.w = f2bf(f.w);
    *(ushort4*)(g_Wb + p*3072 + c) = u;
  }
}

// ------- kernel 2: V transpose  g_Vb[h][s][d] -> g_Vt[h][d][s] -------
__global__ __launch_bounds__(256) void vtrans_kernel() {
  __shared__ __align__(16) unsigned short Ts[64*72];
  const int h  = blockIdx.x;
  const int s0 = blockIdx.y * 64;
  const int d0 = blockIdx.z * 64;
  const int t = threadIdx.x;
  { // load 64 s-rows x 64 d-cols, coalesced
    const int sr = t >> 2;
    const int c  = (t & 3) * 16;
    const unsigned short* src = g_Vb + (h*SEQ + s0 + sr)*HD + d0 + c;
    *(us8*)&Ts[sr*72 + c]     = *(const us8*)&src[0];
    *(us8*)&Ts[sr*72 + c + 8] = *(const us8*)&src[8];
  }
  __syncthreads();
  { // store: wave w covers s-cols [w*16,w*16+16), lane l = output d-row
    const int w = t >> 6, l = t & 63;
    unsigned short outv[16];
    #pragma unroll
    for (int j = 0; j < 16; ++j) outv[j] = Ts[(w*16 + j)*72 + l];
    unsigned short* dst = g_Vt + (h*HD + d0 + l)*SEQ + s0 + w*16;
    *(us8*)&dst[0] = *(us8*)&outv[0];
    *(us8*)&dst[8] = *(us8*)&outv[8];
  }
}

// ------- kernel 3: gate projections via MFMA (M=2048, N=16, K=3072) -------
__global__ __launch_bounds__(256) void gates_kernel() {
  __shared__ f32x4 red[4][64];
  const int tid = threadIdx.x;
  const int wave = tid >> 6, lane = tid & 63;
  const int q4 = lane >> 4, l16 = lane & 15;
  const int s0 = blockIdx.x * 16;
  f32x4 acc = {0.f, 0.f, 0.f, 0.f};
  #pragma unroll 8
  for (int ks = wave*24; ks < wave*24 + 24; ++ks) {
    const int k0 = ks*32 + q4*8;          // global k of this lane's 8 elems
    const int tsel = k0 >> 10;
    const int rem = k0 & 1023;
    const int hh = rem >> 7, dd = rem & 127;
    const unsigned short* base = (tsel == 0) ? g_Qb : (tsel == 1) ? g_Kb : g_Vb;
    const bf16x8 a = *(const bf16x8*)&base[(hh*SEQ + s0 + l16)*HD + dd];
    const bf16x8 b = *(const bf16x8*)&g_Wb[l16*3072 + k0];
    acc = __builtin_amdgcn_mfma_f32_16x16x32_bf16(a, b, acc, 0, 0, 0);
  }
  red[wave][lane] = acc;
  __syncthreads();
  if (wave == 0) {
    f32x4 s = red[0][lane];
    #pragma unroll
    for (int w = 1; w < 4; ++w) s += red[w][lane];
    #pragma unroll
    for (int r = 0; r < 4; ++r) {
      const int sg = s0 + 4*q4 + r;       // C/D: row = quad*4+reg, col = l16
      if (l16 < 8) g_itacc[l16*SEQ + sg] = s[r];
      else         g_ftacc[(l16-8)*SEQ + sg] = s[r];
    }
  }
}

// ------- kernel 4: per-head scans (block scan, 256 threads, 8 elems/thread) -------
__global__ __launch_bounds__(256) void scan_kernel(const float* __restrict__ Wi_b,
                                                   const float* __restrict__ Wf_b) {
  __shared__ float Wsum[4];
  __shared__ float Wmax[4];
  const int h = blockIdx.x;
  const int t = threadIdx.x;
  const int wave = t >> 6, lane = t & 63;
  const float ib = Wi_b[h];
  const float fb = Wf_b[h];
  const int base = h*SEQ + t*8;

  float it[8], ft[8];
  *(float4*)&it[0] = *(const float4*)&g_itacc[base];
  *(float4*)&it[4] = *(const float4*)&g_itacc[base+4];
  *(float4*)&ft[0] = *(const float4*)&g_ftacc[base];
  *(float4*)&ft[4] = *(const float4*)&g_ftacc[base+4];

  float cs[8];
  float run = 0.f;
  #pragma unroll
  for (int j = 0; j < 8; ++j) {
    const float f = ft[j] + fb;
    const float ls = fminf(f, 0.f) - log1pf(expf(-fabsf(f)));  // logsigmoid
    run += ls;
    cs[j] = run;
  }
  float x = run;
  #pragma unroll
  for (int off = 1; off < 64; off <<= 1) {
    const float tv = __shfl_up(x, off, 64);
    if (lane >= off) x += tv;
  }
  const float wexcl = x - run;
  if (lane == 63) Wsum[wave] = x;
  __syncthreads();
  float boff = 0.f;
  #pragma unroll
  for (int w = 0; w < 4; ++w) if (w < wave) boff += Wsum[w];
  const float cbase = boff + wexcl;

  float a[8], am[8], csum[8];
  float m = -__builtin_inff();
  #pragma unroll
  for (int j = 0; j < 8; ++j) {
    csum[j] = cbase + cs[j];
    a[j] = (it[j] + ib) - csum[j];
    m = fmaxf(m, a[j]);
    am[j] = m;
  }
  float y = m;
  #pragma unroll
  for (int off = 1; off < 64; off <<= 1) {
    const float tv = __shfl_up(y, off, 64);
    if (lane >= off) y = fmaxf(y, tv);
  }
  float e = __shfl_up(y, 1, 64);
  if (lane == 0) e = -__builtin_inff();
  if (lane == 63) Wmax[wave] = y;
  __syncthreads();
  float bmax = -__builtin_inff();
  #pragma unroll
  for (int w = 0; w < 4; ++w) if (w < wave) bmax = fmaxf(bmax, Wmax[w]);
  const float pre = fmaxf(bmax, e);

  float oa[8], ocm[8], oen[8];
  #pragma unroll
  for (int j = 0; j < 8; ++j) {
    const float cm = fmaxf(pre, am[j]);
    oa[j]  = a[j] * LOG2E;
    ocm[j] = cm * LOG2E;
    oen[j] = expf(-(csum[j] + cm));
  }
  *(float4*)&g_aL[base]    = *(float4*)&oa[0];
  *(float4*)&g_aL[base+4]  = *(float4*)&oa[4];
  *(float4*)&g_cmL[base]   = *(float4*)&ocm[0];
  *(float4*)&g_cmL[base+4] = *(float4*)&ocm[4];
  *(float4*)&g_en[base]    = *(float4*)&oen[0];
  *(float4*)&g_en[base+4]  = *(float4*)&oen[4];
}

// ------- kernel 5: fused balanced attention + maxit normalize + GroupNorm -------
// grid = (NH, 32): 256 blocks (1/CU); bid%8 = head -> XCD L2 affinity (1.5 MB/head).
// Block y handles the 32-row i-tile PAIR (y, 63-y): causal work = 16-17 visits of
// 128 j-cols for every block (perfect balance, NO partials, NO reduce kernel).
// Per visit: 4 waves own 32-j quarters; K A-frags + V^T B-frags read direct from
// global (L2-hit), double-buffered in registers one visit ahead; both tiles of the
// pair share the K/V frags. Swapped 32x32 MFMA (i = lane&31), in-register P->bf16
// via pack+permlane32_swap. Barrier-free j-loop; epilogue fuses maxit + GroupNorm.
__global__ __launch_bounds__(256, 1) void attn_kernel(const float* __restrict__ gnw,
                                                      const float* __restrict__ gnb,
                                                      float* __restrict__ out) {
  __shared__ float Osum[2][32][132];   // padded rows (132) to spread banks
  __shared__ float Sred[4][32];

  const int h = blockIdx.x;
  const int y = blockIdx.y;            // pair id 0..31
  const int tS = y, tB = 63 - y;
  const int iS0 = 32*tS, iB0 = 32*tB;
  const int iSmax = iS0 + 31, iBmax = iB0 + 31;
  const int nvB = tB/4 + 1;            // 128-col visits for the big tile

  const int tid  = threadIdx.x;
  const int w    = tid >> 6;
  const int lane = tid & 63;
  const int l31  = lane & 31;
  const int hi   = lane >> 5;

  const unsigned short* Kgh = g_Kb + (h*SEQ + l31)*HD + hi*8;   // + jw*HD + ks*16
  const unsigned short* Vgh = g_Vt + (h*HD + l31)*SEQ + hi*8;   // + 32*td*SEQ + jw + 16*ph
  const float*          aLh = g_aL + h*SEQ + 4*hi;              // + jw + 8*rq

  // Q B-fragments (n = i = lane&31) for both tiles
  bf16x8 qfS[8], qfB[8];
  {
    const unsigned short* QS = g_Qb + (h*SEQ + iS0 + l31)*HD + hi*8;
    const unsigned short* QB = g_Qb + (h*SEQ + iB0 + l31)*HD + hi*8;
    #pragma unroll
    for (int ks = 0; ks < 8; ++ks) {
      qfS[ks] = *(const bf16x8*)&QS[ks*16];
      qfB[ks] = *(const bf16x8*)&QB[ks*16];
    }
  }
  const float cmS = g_cmL[h*SEQ + iS0 + l31];
  const float cmB = g_cmL[h*SEQ + iB0 + l31];
  const int   igS = iS0 + l31, igB = iB0 + l31;

  f32x16 accS[4], accB[4];
  #pragma unroll
  for (int td = 0; td < 4; ++td)
    #pragma unroll
    for (int e = 0; e < 16; ++e) { accS[td][e] = 0.f; accB[td][e] = 0.f; }
  float rsS = 0.f, rsB = 0.f;

  bf16x8 Ka[8], Va[8], Kb[8], Vb[8];

  auto LOAD = [&](bf16x8 (&K)[8], bf16x8 (&V)[8], int jc) {
    const int jw = jc*128 + 32*w;
    #pragma unroll
    for (int ks = 0; ks < 8; ++ks)
      K[ks] = *(const bf16x8*)&Kgh[jw*HD + ks*16];
    #pragma unroll
    for (int td = 0; td < 4; ++td)
      #pragma unroll
      for (int ph = 0; ph < 2; ++ph)
        V[td*2 + ph] = *(const bf16x8*)&Vgh[(32*td)*SEQ + jw + 16*ph];
  };

  auto TILE = [&](int jw, const bf16x8 (&K)[8], const bf16x8 (&V)[8],
                  const float4 (&aLq)[4], const bf16x8 (&qf)[8],
                  float cm, int ig, int i0t, f32x16 (&acc)[4], float& rsum) {
    f32x16 s0a, s1a;
    #pragma unroll
    for (int e = 0; e < 16; ++e) { s0a[e] = 0.f; s1a[e] = 0.f; }
    #pragma unroll
    for (int ks = 0; ks < 8; ks += 2) {
      s0a = __builtin_amdgcn_mfma_f32_32x32x16_bf16(K[ks],   qf[ks],   s0a, 0, 0, 0);
      s1a = __builtin_amdgcn_mfma_f32_32x32x16_bf16(K[ks+1], qf[ks+1], s1a, 0, 0, 0);
    }
    const bool needMask = (jw + 31 > i0t);   // wave-uniform
    #pragma unroll
    for (int ph = 0; ph < 2; ++ph) {
      float pv[8];
      if (needMask) {
        #pragma unroll
        for (int rr = 0; rr < 8; ++rr) {
          const int r  = 8*ph + rr;
          const int rq = r >> 2;
          const float aL = ((const float*)&aLq[rq])[r & 3];
          float p = (s0a[r] + s1a[r]) * (exp2f(aL - cm) * INVTAU);
          const int jg = jw + 8*rq + 4*hi + (r & 3);
          if (jg > ig) p = 0.f;
          rsum += p;
          pv[rr] = p;
        }
      } else {
        #pragma unroll
        for (int rr = 0; rr < 8; ++rr) {
          const int r  = 8*ph + rr;
          const int rq = r >> 2;
          const float aL = ((const float*)&aLq[rq])[r & 3];
          const float p = (s0a[r] + s1a[r]) * (exp2f(aL - cm) * INVTAU);
          rsum += p;
          pv[rr] = p;
        }
      }
      const unsigned w0 = packbf(pv[0], pv[1]);
      const unsigned w1 = packbf(pv[2], pv[3]);
      const unsigned w2 = packbf(pv[4], pv[5]);
      const unsigned w3 = packbf(pv[6], pv[7]);
      const auto p0 = __builtin_amdgcn_permlane32_swap(w0, w2, false, false);
      const auto p1 = __builtin_amdgcn_permlane32_swap(w1, w3, false, false);
      union { unsigned u[4]; bf16x8 v; } fr;
      fr.u[0] = p0[0]; fr.u[1] = p1[0]; fr.u[2] = p0[1]; fr.u[3] = p1[1];
      #pragma unroll
      for (int td = 0; td < 4; ++td)
        acc[td] = __builtin_amdgcn_mfma_f32_32x32x16_bf16(fr.v, V[td*2 + ph], acc[td], 0, 0, 0);
    }
  };

  auto STEP = [&](int jc, const bf16x8 (&K)[8], const bf16x8 (&V)[8]) {
    const int jw = jc*128 + 32*w;
    float4 aLq[4];
    #pragma unroll
    for (int rq = 0; rq < 4; ++rq) aLq[rq] = *(const float4*)&aLh[jw + 8*rq];
    if (jw <= iBmax) TILE(jw, K, V, aLq, qfB, cmB, igB, iB0, accB, rsB);
    if (jw <= iSmax) TILE(jw, K, V, aLq, qfS, cmS, igS, iS0, accS, rsS);
  };

  LOAD(Ka, Va, 0);
  int jc = 0;
  for (; jc + 2 <= nvB; jc += 2) {
    LOAD(Kb, Vb, jc + 1);
    STEP(jc, Ka, Va);
    if (jc + 2 < nvB) LOAD(Ka, Va, jc + 2);
    STEP(jc + 1, Kb, Vb);
  }
  if (jc < nvB) STEP(jc, Ka, Va);

  // ---- epilogue: combine 4 waves, maxit-normalize, GroupNorm, store ----
  const float* gw = gnw + h*HD;
  const float* gb = gnb + h*HD;
  auto EPI = [&](f32x16 (&acc)[4], float rsum, int i0t) {
    const float rs2 = rsum + __shfl_xor(rsum, 32, 64);
    if (hi == 0) Sred[w][l31] = rs2;
    if (w >= 2) {   // waves 2,3 store partials
      #pragma unroll
      for (int td = 0; td < 4; ++td)
        #pragma unroll
        for (int r = 0; r < 16; ++r) {
          const int row = (r & 3) + 8*(r >> 2) + 4*hi;
          Osum[w - 2][row][32*td + l31] = acc[td][r];
        }
    }
    __syncthreads();
    if (w < 2) {    // waves 0,1 add theirs (pairwise sums in Osum[0],Osum[1])
      #pragma unroll
      for (int td = 0; td < 4; ++td)
        #pragma unroll
        for (int r = 0; r < 16; ++r) {
          const int row = (r & 3) + 8*(r >> 2) + 4*hi;
          Osum[w][row][32*td + l31] += acc[td][r];
        }
    }
    __syncthreads();
    const int i  = tid >> 3;
    const int d0 = (tid & 7) * 16;
    float o[16];
    #pragma unroll
    for (int e = 0; e < 16; e += 4) {
      const float4 a0 = *(const float4*)&Osum[0][i][d0 + e];
      const float4 a1 = *(const float4*)&Osum[1][i][d0 + e];
      o[e+0] = a0.x + a1.x; o[e+1] = a0.y + a1.y;
      o[e+2] = a0.z + a1.z; o[e+3] = a0.w + a1.w;
    }
    const float S  = Sred[0][i] + Sred[1][i] + Sred[2][i] + Sred[3][i];
    const float en = g_en[h*SEQ + i0t + i];
    const float sc = 1.f / (fmaxf(fabsf(S), en) + 1e-6f);
    float s1 = 0.f, s2 = 0.f;
    #pragma unroll
    for (int e = 0; e < 16; ++e) { const float xv = o[e]*sc; o[e] = xv; s1 += xv; s2 += xv*xv; }
    #pragma unroll
    for (int m = 1; m < 8; m <<= 1) { s1 += __shfl_xor(s1, m, 8); s2 += __shfl_xor(s2, m, 8); }
    const float mean = s1 * (1.f/128.f);
    const float var  = s2 * (1.f/128.f) - mean*mean;
    const float rstd = rsqrtf(var + 1e-5f);
    float* op = out + (i0t + i)*DIMF + h*HD + d0;
    #pragma unroll
    for (int e = 0; e < 16; e += 4) {
      const float4 w4 = *(const float4*)&gw[d0 + e];
      const float4 b4 = *(const float4*)&gb[d0 + e];
      float4 ov;
      ov.x = (o[e+0] - mean) * rstd * w4.x + b4.x;
      ov.y = (o[e+1] - mean) * rstd * w4.y + b4.y;
      ov.z = (o[e+2] - mean) * rstd * w4.z + b4.z;
      ov.w = (o[e+3] - mean) * rstd * w4.w + b4.w;
      *(float4*)&op[e] = ov;
    }
  };

  EPI(accS, rsS, iS0);
  __syncthreads();
  EPI(accB, rsB, iB0);
}

extern "C" void kernel_launch(void* const* d_in, const int* in_sizes, int n_in,
                              void* d_out, int out_size, void* d_ws, size_t ws_size,
                              hipStream_t stream) {
  (void)in_sizes; (void)n_in; (void)out_size; (void)d_ws; (void)ws_size;
  const float* q    = (const float*)d_in[0];
  const float* k    = (const float*)d_in[1];
  const float* v    = (const float*)d_in[2];
  const float* Wi_w = (const float*)d_in[3];
  const float* Wi_b = (const float*)d_in[4];
  const float* Wf_w = (const float*)d_in[5];
  const float* Wf_b = (const float*)d_in[6];
  const float* gnw  = (const float*)d_in[7];
  const float* gnb  = (const float*)d_in[8];
  float* out = (float*)d_out;

  convert_kernel<<<dim3(6192), 256, 0, stream>>>(q, k, v, Wi_w, Wf_w);
  vtrans_kernel<<<dim3(NH, SEQ/64, HD/64), 256, 0, stream>>>();
  gates_kernel<<<dim3(128), 256, 0, stream>>>();
  scan_kernel<<<dim3(NH), 256, 0, stream>>>(Wi_b, Wf_b);
  attn_kernel<<<dim3(NH, 32), 256, 0, stream>>>(gnw, gnb, out);
}